// Round 8
// baseline (1613.307 us; speedup 1.0000x reference)
//
#include <hip/hip_runtime.h>

// PointerNet: B=4, N=128, H=512, d_pair=256.
// WORLD-B INTERFACE (the only one consistent with all 8 rounds of evidence):
//   inputs  f32, setup_inputs dict order
//   d_out   f32, 50,724,864 elements = [4][128][128][774]
// Per mlp g in {future(Wf1,Wf2,w3), hist1(Wh1a,Wh1b,wl1), hist2(Wh2a,Wh2b,wl2)}:
//   uv[m][c'] = sum_h P[m][h] * W1[(c'>=1024?512:0)+h][c'&1023]     (m = b*128+i)
//   y[bi,j,n] = relu( sum_k relu(uv[bi][k] + uv[bj][1024+k]) * W2[k][n] )
//   p = softmax_c( sum_n y[n] * w3[n][c] )
//   out[((bi)*128+j)*774 + g*258 + {n | 256+c}] = {y | p}
// Workspace: uv f32 [512][2048] = 4,194,304 B at ws+0 (reused per mlp).

typedef __attribute__((ext_vector_type(4))) float floatx4;
typedef __attribute__((ext_vector_type(2))) float floatx2;

#define KT 16
#define LSTRIDE 68  // 64 + 4 pad (LDS bank-conflict break)

// ---------------------------------------------------------------------------
// Kernel 1: stage1 f32 GEMM. Block = 64m x 64c tile; 256 thr = 16x16, each
// thread 4x4 outputs. K-tiles of 16 staged in LDS (A transposed at load).
// Grid 256 = 8 m-blk x 32 c-blk.
// ---------------------------------------------------------------------------
__global__ __launch_bounds__(256) void stage1_valu(
    const float* __restrict__ P,    // [512][512]
    const float* __restrict__ W1,   // [1024][1024], one mlp
    float* __restrict__ uv) {       // [512][2048]
  __shared__ float at[KT][LSTRIDE];  // at[k][m]
  __shared__ float wt[KT][LSTRIDE];  // wt[k][c]
  int bx = blockIdx.x;
  int m0 = (bx >> 5) * 64;
  int c0 = (bx & 31) * 64;
  int half = c0 >> 10;            // 0: u-half (W1 rows 0..511), 1: v-half
  int ccol = c0 & 1023;
  int tid = threadIdx.x;
  int tm = tid >> 4, tn = tid & 15;
  int lm = tid >> 2;              // 0..63  A-load row
  int lk4 = (tid & 3) * 4;        // A-load k chunk
  int lkk = tid >> 4;             // 0..15  W-load k row
  int lc4 = (tid & 15) * 4;       // W-load c chunk

  float acc[4][4] = {};

  for (int k0 = 0; k0 < 512; k0 += KT) {
    floatx4 pa = *(const floatx4*)(P + (long)(m0 + lm) * 512 + k0 + lk4);
    floatx4 wa = *(const floatx4*)(W1 + (long)(half * 512 + k0 + lkk) * 1024 + ccol + lc4);
    __syncthreads();              // prev-iter LDS reads done
#pragma unroll
    for (int e = 0; e < 4; e++) at[lk4 + e][lm] = pa[e];
    *(floatx4*)&wt[lkk][lc4] = wa;
    __syncthreads();
#pragma unroll
    for (int kk = 0; kk < KT; kk++) {
      floatx4 av = *(const floatx4*)&at[kk][tm * 4];
      floatx4 wv = *(const floatx4*)&wt[kk][tn * 4];
#pragma unroll
      for (int mm = 0; mm < 4; mm++)
#pragma unroll
        for (int nn = 0; nn < 4; nn++)
          acc[mm][nn] += av[mm] * wv[nn];
    }
  }
#pragma unroll
  for (int mm = 0; mm < 4; mm++) {
    floatx4 o;
#pragma unroll
    for (int nn = 0; nn < 4; nn++) o[nn] = acc[mm][nn];
    *(floatx4*)(uv + (long)(m0 + tm * 4 + mm) * 2048 + c0 + tn * 4) = o;
  }
}

// ---------------------------------------------------------------------------
// Kernel 2 (hot): pair GEMM, f32 VALU. Block = (bi, 64-j half, 64-n quarter):
// y[64j x 64n] = relu( relu(u+v) @ W2 ), W2 row-major direct. z built into
// LDS per k-tile. Grid 4096 per mlp. OUTPUT STORES ARE F32 (floatx2: the
// element offset is even but 774-row stride makes %4 vary -> 8B alignment).
// ---------------------------------------------------------------------------
__global__ __launch_bounds__(256) void pair_valu(
    const float* __restrict__ uv,   // [512][2048], this mlp
    const float* __restrict__ W2,   // [1024][256], this mlp
    float* __restrict__ out, int mlp) {
  __shared__ float zt[KT][LSTRIDE];  // zt[k][j]
  __shared__ float wt[KT][LSTRIDE];  // wt[k][n]
  int bx = blockIdx.x;               // 4096 = 512 bi x 2 jh x 4 nb
  int nb = bx & 3;
  int jh = (bx >> 2) & 1;
  int bi = bx >> 3;                  // b*128 + i
  int b = bi >> 7;
  int j0 = jh * 64;
  int n0 = nb * 64;
  int tid = threadIdx.x;
  int tm = tid >> 4, tn = tid & 15;
  int lj = tid >> 2;                 // 0..63  z-load j row
  int lk4 = (tid & 3) * 4;           // z-load k chunk
  int lkk = tid >> 4;                // 0..15  W-load k row
  int ln4 = (tid & 15) * 4;          // W-load n chunk

  const float* urow = uv + (long)bi * 2048;
  const float* vrow = uv + (long)(b * 128 + j0 + lj) * 2048 + 1024;

  float acc[4][4] = {};

  for (int k0 = 0; k0 < 1024; k0 += KT) {
    floatx4 uu = *(const floatx4*)(urow + k0 + lk4);
    floatx4 vv = *(const floatx4*)(vrow + k0 + lk4);
    floatx4 wa = *(const floatx4*)(W2 + (long)(k0 + lkk) * 256 + n0 + ln4);
    __syncthreads();
#pragma unroll
    for (int e = 0; e < 4; e++) {
      float z = uu[e] + vv[e];
      zt[lk4 + e][lj] = z > 0.f ? z : 0.f;
    }
    *(floatx4*)&wt[lkk][ln4] = wa;
    __syncthreads();
#pragma unroll
    for (int kk = 0; kk < KT; kk++) {
      floatx4 zv = *(const floatx4*)&zt[kk][tm * 4];
      floatx4 wv = *(const floatx4*)&wt[kk][tn * 4];
#pragma unroll
      for (int mm = 0; mm < 4; mm++)
#pragma unroll
        for (int nn = 0; nn < 4; nn++)
          acc[mm][nn] += zv[mm] * wv[nn];
    }
  }
  // epilogue: y = relu(acc), f32 stores; thread owns j=j0+tm*4+mm, n=n0+tn*4+nn
  float* ob = out + (long)(bi * 128 + j0) * 774 + mlp * 258 + n0 + tn * 4;
#pragma unroll
  for (int mm = 0; mm < 4; mm++) {
    float* orow = ob + (long)(tm * 4 + mm) * 774;
    floatx2 pa, pb;
    pa[0] = acc[mm][0] > 0.f ? acc[mm][0] : 0.f;
    pa[1] = acc[mm][1] > 0.f ? acc[mm][1] : 0.f;
    pb[0] = acc[mm][2] > 0.f ? acc[mm][2] : 0.f;
    pb[1] = acc[mm][3] > 0.f ? acc[mm][3] : 0.f;
    *(floatx2*)orow = pa;          // even element offset -> 8B aligned
    *(floatx2*)(orow + 2) = pb;
  }
}

// ---------------------------------------------------------------------------
// Kernel 3: heads. One wave per (g,row): s = y(256) @ w3(256x2) (y read back
// f32 from out), softmax, write 2 f32 at +256.
// ---------------------------------------------------------------------------
__global__ __launch_bounds__(256) void head_kernel(
    const float* __restrict__ w3_0, const float* __restrict__ w3_1,
    const float* __restrict__ w3_2, float* out) {
  int wid = threadIdx.x >> 6, lane = threadIdx.x & 63;
  int r = blockIdx.x * 4 + wid;   // [0, 196608)
  int mlp = r >> 16;
  int row = r & 65535;            // (b*128+i)*128 + j
  const float* w3 = (mlp == 0) ? w3_0 : (mlp == 1) ? w3_1 : w3_2;
  const float* yp = out + (long)row * 774 + mlp * 258 + lane * 4;
  floatx2 ya = *(const floatx2*)yp;        // even elem offset -> 8B aligned
  floatx2 yb = *(const floatx2*)(yp + 2);
  const float* wp = w3 + lane * 8;         // 32B-aligned
  floatx4 wv0 = *(const floatx4*)wp;       // rows n=lane*4, lane*4+1 (c pairs)
  floatx4 wv1 = *(const floatx4*)(wp + 4); // rows n=lane*4+2, +3
  float s0 = ya[0] * wv0[0] + ya[1] * wv0[2] + yb[0] * wv1[0] + yb[1] * wv1[2];
  float s1 = ya[0] * wv0[1] + ya[1] * wv0[3] + yb[0] * wv1[1] + yb[1] * wv1[3];
#pragma unroll
  for (int off = 32; off > 0; off >>= 1) {
    s0 += __shfl_xor(s0, off, 64);
    s1 += __shfl_xor(s1, off, 64);
  }
  if (lane == 0) {
    float m = fmaxf(s0, s1);
    float e0 = __expf(s0 - m), e1 = __expf(s1 - m);
    float inv = 1.0f / (e0 + e1);
    floatx2 pr;
    pr[0] = e0 * inv;
    pr[1] = e1 * inv;
    *(floatx2*)(out + (long)row * 774 + mlp * 258 + 256) = pr;
  }
}

extern "C" void kernel_launch(void* const* d_in, const int* in_sizes, int n_in,
                              void* d_out, int out_size, void* d_ws, size_t ws_size,
                              hipStream_t stream) {
  const float* para = (const float*)d_in[0];
  const float* Wf1  = (const float*)d_in[1];
  const float* Wf2  = (const float*)d_in[2];
  const float* w3   = (const float*)d_in[3];
  const float* Wh1a = (const float*)d_in[4];
  const float* Wh1b = (const float*)d_in[5];
  const float* wl1  = (const float*)d_in[6];
  const float* Wh2a = (const float*)d_in[7];
  const float* Wh2b = (const float*)d_in[8];
  const float* wl2  = (const float*)d_in[9];

  float* uv = (float*)d_ws;                  // 4,194,304 B
  float* outp = (float*)d_out;               // f32 [4*128*128][774]

  const float* W1s[3] = {Wf1, Wh1a, Wh2a};
  const float* W2s[3] = {Wf2, Wh1b, Wh2b};
  for (int mlp = 0; mlp < 3; mlp++) {
    stage1_valu<<<256, 256, 0, stream>>>(para, W1s[mlp], uv);
    pair_valu<<<4096, 256, 0, stream>>>(uv, W2s[mlp], outp, mlp);
  }
  head_kernel<<<49152, 256, 0, stream>>>(w3, wl1, wl2, outp);
}